// Round 7
// baseline (626.982 us; speedup 1.0000x reference)
//
#include <hip/hip_runtime.h>
#include <stdint.h>

// MemoryDiscriminator: embed-GEMM + LeakyReLU + BN(fold into GEMM2) + dual GRU scan + cosine gate.
// Key identities: hm is batch-uniform; only t=T-1 output needed; gi_x hoisted out of scan.
// R7: (a) producer writes PERMUTED gi layout: each consumer lane's 24 gate scalars for step t are
//     48 contiguous bytes -> consumer loads 3 x dwordx4 per step into VGPRs (R6 used 24 scalars).
//     (b) consumer barrier = raw "s_waitcnt lgkmcnt(0); s_barrier" (NO vmcnt drain) so gate
//     prefetch for t+2 stays in flight ~2 steps (R5/R6: __syncthreads drained vmcnt every step).
//     (c) producer n-fused to 128x384 tiles: eact read 2x not 6x, flag threshold 2.

typedef float  f32x4 __attribute__((ext_vector_type(4)));
typedef __bf16 bf16x8 __attribute__((ext_vector_type(8)));
typedef unsigned short u16;

#define B_   256
#define T_   128

// ---------------- workspace layout (bytes) ----------------
static constexpr size_t OFF_XB    = 0;          // 32768*128 bf16   = 8,388,608
static constexpr size_t OFF_WEMB  = 8388608;    // 1024*128 bf16    = 262,144
static constexpr size_t OFF_WHX   = 8650752;    // 768*256 bf16     = 393,216
static constexpr size_t OFF_WHM   = 9043968;    // 768*256 bf16     = 393,216
static constexpr size_t OFF_SUM   = 9437184;    // 1024 f32
static constexpr size_t OFF_SSQ   = 9441280;    // 1024 f32
static constexpr size_t OFF_FLAGS = 9445376;    // 256 int (tile-ready flags, zeroed by prep)
static constexpr size_t OFF_BIASX = 9453568;    // 768 f32 (padded)
static constexpr size_t OFF_GIM   = 9457664;    // 128*768 bf16     = 196,608
static constexpr size_t OFF_EACT  = 9654272;    // 32768*1024 bf16  = 67,108,864
static constexpr size_t OFF_GI    = 76763136;   // gperm: 128t*16wg*8v*64lane*24 u16 = 50,331,648
static constexpr size_t OFF_HXF   = 127094784;  // 256*256 f32
static constexpr size_t OFF_HMF   = 127356928;  // 16*256 f32
static constexpr size_t OFF_WPX   = 127373312;  // 768*1024 bf16    = 1,572,864
// total ~128.9 MB

__device__ __forceinline__ float sigmoidf_(float x) {
    return __builtin_amdgcn_rcpf(1.0f + __expf(-x));
}
__device__ __forceinline__ float tanhf_(float x) {
    return 1.0f - 2.0f * __builtin_amdgcn_rcpf(1.0f + __expf(2.0f * x));
}
__device__ __forceinline__ float bf16bits_(u16 u) {
    return __uint_as_float(((unsigned)u) << 16);
}
__device__ __forceinline__ u16 f2bf_(float f) {
    __bf16 h = (__bf16)f;
    return __builtin_bit_cast(u16, h);
}
__device__ __forceinline__ void gload_lds16(const void* g, void* l) {
    __builtin_amdgcn_global_load_lds(
        (const __attribute__((address_space(1))) unsigned int*)g,
        (__attribute__((address_space(3))) unsigned int*)l, 16, 0, 0);
}
// barrier that orders LDS only -- leaves global loads (vmcnt) in flight across it
__device__ __forceinline__ void barrier_nodrain() {
    __asm__ volatile("s_waitcnt lgkmcnt(0)\n\ts_barrier" ::: "memory");
}

// ---------------- K0: fp32->bf16 conversions + zero stats & flags ----------------
__global__ void prep(const float* __restrict__ x, const float* __restrict__ wemb,
                     const float* __restrict__ whx, const float* __restrict__ whm,
                     __bf16* __restrict__ xb, __bf16* __restrict__ wembb,
                     __bf16* __restrict__ whxb, __bf16* __restrict__ whmb,
                     float* __restrict__ stats /*2048*/, int* __restrict__ flags /*256*/)
{
    long i = (long)blockIdx.x * 256 + threadIdx.x;
    if (i < 2048) stats[i] = 0.0f;
    else if (i < 2304) flags[i - 2048] = 0;
    if (i < 4194304)      xb[i] = (__bf16)x[i];
    else if (i < 4325376) wembb[i - 4194304] = (__bf16)wemb[i - 4194304];
    else if (i < 4521984) whxb[i - 4325376]  = (__bf16)whx[i - 4325376];
    else if (i < 4718592) whmb[i - 4521984]  = (__bf16)whm[i - 4521984];
}

// ---------------- K1: eact GEMM (+bias, LeakyReLU, BN stats), 128x128 tile, BK=32 ----------------
__launch_bounds__(256)
__global__ void gemm_e(const __bf16* __restrict__ A, const __bf16* __restrict__ Bm,
                       const float* __restrict__ bias, __bf16* __restrict__ C,
                       float* __restrict__ sums, float* __restrict__ ssqs,
                       int K, int N)
{
    __shared__ __bf16 As[128 * 32];
    __shared__ __bf16 Bs[128 * 32];
    const int tid  = threadIdx.x;
    const int lane = tid & 63;
    const int wv   = tid >> 6;
    const int wm   = wv >> 1, wn = wv & 1;
    const int l15  = lane & 15, quad = lane >> 4;
    const long m0 = (long)blockIdx.x * 128;
    const long n0 = (long)blockIdx.y * 128;

    const int srow = lane >> 2;
    const int scol = (lane & 3) * 8;
    const __bf16* ag[2]; const __bf16* bg[2];
    __bf16* al[2]; __bf16* bl[2];
#pragma unroll
    for (int j = 0; j < 2; j++) {
        const int s = wv * 2 + j;
        ag[j] = A  + (m0 + s * 16 + srow) * K + scol;
        bg[j] = Bm + (n0 + s * 16 + srow) * K + scol;
        al[j] = &As[s * 512];
        bl[j] = &Bs[s * 512];
    }

    const f32x4 fz = {0.f, 0.f, 0.f, 0.f};
    f32x4 acc[4][4];
#pragma unroll
    for (int i = 0; i < 4; i++)
#pragma unroll
        for (int j = 0; j < 4; j++) acc[i][j] = fz;

    for (int k0 = 0; k0 < K; k0 += 32) {
        __syncthreads();
        gload_lds16(ag[0] + k0, al[0]);
        gload_lds16(ag[1] + k0, al[1]);
        gload_lds16(bg[0] + k0, bl[0]);
        gload_lds16(bg[1] + k0, bl[1]);
        __syncthreads();
        bf16x8 af[4], bfr[4];
#pragma unroll
        for (int mt = 0; mt < 4; mt++)
            af[mt] = *(const bf16x8*)(&As[(wm * 64 + mt * 16 + l15) * 32 + quad * 8]);
#pragma unroll
        for (int nt = 0; nt < 4; nt++)
            bfr[nt] = *(const bf16x8*)(&Bs[(wn * 64 + nt * 16 + l15) * 32 + quad * 8]);
#pragma unroll
        for (int mt = 0; mt < 4; mt++)
#pragma unroll
            for (int nt = 0; nt < 4; nt++)
                acc[mt][nt] = __builtin_amdgcn_mfma_f32_16x16x32_bf16(af[mt], bfr[nt], acc[mt][nt], 0, 0, 0);
    }

#pragma unroll
    for (int nt = 0; nt < 4; nt++) {
        const long ncol = n0 + wn * 64 + nt * 16 + l15;
        const float bi = bias[ncol];
        float s = 0.f, ss = 0.f;
#pragma unroll
        for (int mt = 0; mt < 4; mt++) {
#pragma unroll
            for (int r = 0; r < 4; r++) {
                float v = acc[mt][nt][r] + bi;
                v = (v >= 0.f) ? v : 0.2f * v;
                __bf16 hv = (__bf16)v;
                C[(m0 + wm * 64 + mt * 16 + quad * 4 + r) * (long)N + ncol] = hv;
                float fv = (float)hv; s += fv; ss += fv * fv;
            }
        }
        s += __shfl_xor(s, 16);  ss += __shfl_xor(ss, 16);
        s += __shfl_xor(s, 32);  ss += __shfl_xor(ss, 32);
        if (lane < 16) {
            atomicAdd(&sums[n0 + wn * 64 + nt * 16 + lane], s);
            atomicAdd(&ssqs[n0 + wn * 64 + nt * 16 + lane], ss);
        }
    }
}

// ---------------- K2: build_wp (blocks 0..767) + build_gim (blocks 768..3839) merged ----------------
__global__ void build_misc(const float* __restrict__ w_ih_x, const float* __restrict__ b_ih_x,
                           const float* __restrict__ b_hh_x, const float* __restrict__ sums,
                           const float* __restrict__ ssqs, const float* __restrict__ gamma,
                           const float* __restrict__ beta, __bf16* __restrict__ wpx,
                           float* __restrict__ biasx,
                           const float* __restrict__ memory, const float* __restrict__ w_ih_m,
                           const float* __restrict__ b_ih_m, const float* __restrict__ b_hh_m,
                           __bf16* __restrict__ gim)
{
    const int lane = threadIdx.x;  // 64
    if (blockIdx.x < 768) {
        const int j = blockIdx.x;
        const float inv = 1.0f / 32768.0f;
        float accv = 0.f;
#pragma unroll
        for (int i = 0; i < 16; i++) {
            int h = i * 64 + lane;
            float mean = sums[h] * inv;
            float var  = ssqs[h] * inv - mean * mean;
            float s    = rsqrtf(var + 1e-5f) * gamma[h];
            float c    = beta[h] - mean * s;
            float w = w_ih_x[(long)j * 1024 + h];
            wpx[(long)j * 1024 + h] = (__bf16)(w * s);
            accv += c * w;
        }
        for (int off = 32; off; off >>= 1) accv += __shfl_xor(accv, off);
        if (lane == 0) biasx[j] = accv + b_ih_x[j] + (j < 512 ? b_hh_x[j] : 0.0f);
    } else {
        const int g  = blockIdx.x - 768;
        const int jj = g % 768;
        const int t0 = (g / 768) * 32;
        float w[16];
#pragma unroll
        for (int i = 0; i < 16; i++) w[i] = w_ih_m[(long)jj * 1024 + i * 64 + lane];
        const float bb = b_ih_m[jj] + (jj < 512 ? b_hh_m[jj] : 0.0f);
        for (int t = t0; t < t0 + 32; t++) {
            float s = 0.f;
#pragma unroll
            for (int i = 0; i < 16; i++) s += w[i] * memory[(long)t * 1024 + i * 64 + lane];
            for (int off = 32; off; off >>= 1) s += __shfl_xor(s, off);
            if (lane == 0) gim[t * 768 + jj] = (__bf16)(s + bb);
        }
    }
}

// ---------------- K3: FUSED gi-GEMM producer + GRU recurrence consumer ----------------
// blockIdx 0..16: recurrence (wg<16: 16 batch rows; wg16: hm). blockIdx 17..528: producer tiles,
// g = bx-17, mt = g>>1 (t-order), nh = g&1 (384-col half). gperm layout per element:
//   u16 index = ((t*16 + wg)*8 + v)*1536 + lane*24 + g*8 + r*2 + ct
// (wg = batch-row/16, v = consumer wave owning cols [32v,32v+32), lane = quad*16+l15,
//  r = row quad*4+r, ct = col half, g = gate). 84KB LDS pad -> 1 wg/CU everywhere.
__launch_bounds__(512, 2)
__global__ void fused(const __bf16* __restrict__ eact, const __bf16* __restrict__ wpx,
                      const float* __restrict__ biasx, __bf16* __restrict__ gperm,
                      const __bf16* __restrict__ gim,
                      const __bf16* __restrict__ whx, const __bf16* __restrict__ whm,
                      const float* __restrict__ bhhx, const float* __restrict__ bhhm,
                      float* __restrict__ hxfin, float* __restrict__ hmfin,
                      int* __restrict__ flags)
{
    __shared__ union {
        struct { __bf16 hxl[2][16 * 264]; } rec;                   // 16,896 B
        struct { __bf16 As[128 * 32]; __bf16 Bs[384 * 32]; } gm;   // 32,768 B
        char pad[83968];                                            // force 1 wg/CU
    } sm;

    const int tid  = threadIdx.x;
    const int lane = tid & 63;
    const int v    = tid >> 6;     // wave 0..7
    const int l15  = lane & 15, quad = lane >> 4;

    if (blockIdx.x >= 17) {
        // ---------------- producer: one 128x384 tile (one t, half the batch, half the cols) ----
        const int g   = blockIdx.x - 17;   // 0..511
        const int mt  = g >> 1;            // 0..255
        const int nh  = g & 1;
        const int t   = mt >> 1, bhalf = mt & 1;
        const int c0  = nh * 384;
        const int mh  = v >> 2, q = v & 3; // wave: rows mh*64+.., cols q*96+..
        const int srow = lane >> 2, scol = (lane & 3) * 8;

        // staging: wave v stages As rows [v*16,v*16+16), Bs rows [v*48,v*48+48)
        const __bf16* agA = eact + ((long)(bhalf * 128 + v * 16 + srow) * 128 + t) * 1024 + scol;
        __bf16* alA = &sm.gm.As[v * 512];
        const __bf16* agB[3]; __bf16* blB[3];
#pragma unroll
        for (int sub = 0; sub < 3; sub++) {
            agB[sub] = wpx + (long)(c0 + v * 48 + sub * 16 + srow) * 1024 + scol;
            blB[sub] = &sm.gm.Bs[(v * 3 + sub) * 512];
        }

        const f32x4 fz = {0.f, 0.f, 0.f, 0.f};
        f32x4 acc[4][6];
#pragma unroll
        for (int i = 0; i < 4; i++)
#pragma unroll
            for (int j = 0; j < 6; j++) acc[i][j] = fz;

        for (int k0 = 0; k0 < 1024; k0 += 32) {
            __syncthreads();
            gload_lds16(agA + k0, alA);
            gload_lds16(agB[0] + k0, blB[0]);
            gload_lds16(agB[1] + k0, blB[1]);
            gload_lds16(agB[2] + k0, blB[2]);
            __syncthreads();
            bf16x8 af[4], bfr[6];
#pragma unroll
            for (int i = 0; i < 4; i++)
                af[i] = *(const bf16x8*)(&sm.gm.As[(mh * 64 + i * 16 + l15) * 32 + quad * 8]);
#pragma unroll
            for (int j = 0; j < 6; j++)
                bfr[j] = *(const bf16x8*)(&sm.gm.Bs[(q * 96 + j * 16 + l15) * 32 + quad * 8]);
#pragma unroll
            for (int i = 0; i < 4; i++)
#pragma unroll
                for (int j = 0; j < 6; j++)
                    acc[i][j] = __builtin_amdgcn_mfma_f32_16x16x32_bf16(af[i], bfr[j], acc[i][j], 0, 0, 0);
        }

        float bi[6];
#pragma unroll
        for (int j = 0; j < 6; j++) bi[j] = biasx[c0 + q * 96 + j * 16 + l15];

        u16* gp = (u16*)gperm;
#pragma unroll
        for (int i = 0; i < 4; i++) {
            const int wgi = bhalf * 8 + mh * 4 + i;
#pragma unroll
            for (int jp = 0; jp < 3; jp++) {
                const int cbase = c0 + q * 96 + jp * 32;
                const int gg = cbase >> 8;
                const int vc = (cbase >> 5) & 7;
                unsigned wbits[4];
#pragma unroll
                for (int r = 0; r < 4; r++) {
                    u16 lo = f2bf_(acc[i][2 * jp + 0][r] + bi[2 * jp + 0]);
                    u16 hi = f2bf_(acc[i][2 * jp + 1][r] + bi[2 * jp + 1]);
                    wbits[r] = (unsigned)lo | ((unsigned)hi << 16);
                }
                uint4 o = {wbits[0], wbits[1], wbits[2], wbits[3]};
                const long idx = (((long)t * 16 + wgi) * 8 + vc) * 1536 + (long)lane * 24 + gg * 8;
                *(uint4*)(gp + idx) = o;
            }
        }
        __syncthreads();   // drains stores (vmcnt) before release
        if (tid == 0)
            __hip_atomic_fetch_add(&flags[mt], 1, __ATOMIC_RELEASE, __HIP_MEMORY_SCOPE_AGENT);
        return;
    }

    // ---------------- consumer: GRU recurrence (8-wave shape, VGPR gate prefetch depth-2) ------
    const int wg   = blockIdx.x;   // 0..16
    const bool isX = (wg < 16);
    const __bf16* wh  = isX ? whx : whm;
    const float*  bhh = isX ? bhhx : bhhm;

    bf16x8 W[6][8];
#pragma unroll
    for (int nt = 0; nt < 6; nt++) {
        const int gg = nt >> 1, ct = nt & 1;
        const long j = gg * 256 + (v * 2 + ct) * 16 + l15;
#pragma unroll
        for (int kt = 0; kt < 8; kt++)
            W[nt][kt] = *(const bf16x8*)(wh + j * 256 + kt * 32 + quad * 8);
    }
    float bhhn[2];
#pragma unroll
    for (int ct = 0; ct < 2; ct++) bhhn[ct] = bhh[512 + v * 32 + ct * 16 + l15];

    for (int i = tid; i < 16 * 264; i += 512) sm.rec.hxl[0][i] = (__bf16)0.f;

    float st[8];
#pragma unroll
    for (int i = 0; i < 8; i++) st[i] = 0.f;

    // gate-data pointers
    const char* gpbase = (const char*)gperm + ((long)wg * 8 + v) * 3072 + (long)lane * 48;
    const int colb = v * 32 + l15;
    const int myhalf = wg >> 3;

    int ready = -1;
    auto wait_tile = [&](int tt) {
        if (!isX) return;
        const int need = 2 * tt + myhalf;
        if (need <= ready) return;
        int probe = need + 28; if (probe > 255) probe = 255;
        if (__hip_atomic_load(&flags[probe], __ATOMIC_ACQUIRE, __HIP_MEMORY_SCOPE_AGENT) >= 2) {
            ready = probe; return;
        }
        while (__hip_atomic_load(&flags[need], __ATOMIC_ACQUIRE, __HIP_MEMORY_SCOPE_AGENT) < 2)
            __builtin_amdgcn_s_sleep(2);
        ready = need;
    };

    uint4 qa[3], qb[3];
    u16   ha[6], hb[6];
    auto load_vec = [&](int t, uint4* qd) {
        const char* p = gpbase + (long)t * 393216;   // 16*8*3072 per step
        qd[0] = *(const uint4*)(p);
        qd[1] = *(const uint4*)(p + 16);
        qd[2] = *(const uint4*)(p + 32);
    };
    auto load_hm = [&](int t, u16* hd) {
        const u16* p = (const u16*)gim + (long)t * 768 + colb;
#pragma unroll
        for (int gg = 0; gg < 3; gg++)
#pragma unroll
            for (int ct = 0; ct < 2; ct++) hd[gg * 2 + ct] = p[gg * 256 + ct * 16];
    };

    wait_tile(0); wait_tile(1);
    if (isX) { load_vec(0, qa); load_vec(1, qb); }
    else     { load_hm(0, ha);  load_hm(1, hb);  }
    __syncthreads();   // hxl[0] zero-init visible (full drain ok before loop)

    int cur = 0;
    auto do_step = [&](const uint4* qc, const u16* hc) {
        const f32x4 fz = {0.f, 0.f, 0.f, 0.f};
        f32x4 acc[6];
#pragma unroll
        for (int nt = 0; nt < 6; nt++) acc[nt] = fz;
        const __bf16* hxc = &sm.rec.hxl[cur][0];
#pragma unroll
        for (int kt = 0; kt < 8; kt++) {
            bf16x8 a = *(const bf16x8*)(hxc + l15 * 264 + kt * 32 + quad * 8);
#pragma unroll
            for (int nt = 0; nt < 6; nt++)
                acc[nt] = __builtin_amdgcn_mfma_f32_16x16x32_bf16(a, W[nt][kt], acc[nt], 0, 0, 0);
        }
        __bf16* hxn = &sm.rec.hxl[cur ^ 1][0];
        unsigned wr4[4], wz4[4], wn4[4];
        if (isX) {
            wr4[0] = qc[0].x; wr4[1] = qc[0].y; wr4[2] = qc[0].z; wr4[3] = qc[0].w;
            wz4[0] = qc[1].x; wz4[1] = qc[1].y; wz4[2] = qc[1].z; wz4[3] = qc[1].w;
            wn4[0] = qc[2].x; wn4[1] = qc[2].y; wn4[2] = qc[2].z; wn4[3] = qc[2].w;
        }
#pragma unroll
        for (int ct = 0; ct < 2; ct++) {
            const int ob = v * 32 + ct * 16 + l15;
#pragma unroll
            for (int r = 0; r < 4; r++) {
                float gr, gz, gn;
                if (isX) {
                    gr = __uint_as_float((ct ? (wr4[r] & 0xffff0000u) : (wr4[r] << 16)));
                    gz = __uint_as_float((ct ? (wz4[r] & 0xffff0000u) : (wz4[r] << 16)));
                    gn = __uint_as_float((ct ? (wn4[r] & 0xffff0000u) : (wn4[r] << 16)));
                } else {
                    gr = bf16bits_(hc[0 * 2 + ct]);
                    gz = bf16bits_(hc[1 * 2 + ct]);
                    gn = bf16bits_(hc[2 * 2 + ct]);
                }
                const float rg = sigmoidf_(gr + acc[ct][r]);
                const float zg = sigmoidf_(gz + acc[2 + ct][r]);
                const float ng = tanhf_(gn + rg * (acc[4 + ct][r] + bhhn[ct]));
                float h = st[ct * 4 + r];
                h = ng + zg * (h - ng);
                st[ct * 4 + r] = h;
                hxn[(quad * 4 + r) * 264 + ob] = (__bf16)h;
            }
        }
    };

    for (int t = 0; t < 128; t += 2) {
        do_step(qa, ha);                       // step t (even) consumes buffer A
        if (t + 2 < 128) {
            wait_tile(t + 2);
            if (isX) load_vec(t + 2, qa); else load_hm(t + 2, ha);
        }
        barrier_nodrain();                     // LDS-only barrier: prefetch stays in flight
        cur ^= 1;
        do_step(qb, hb);                       // step t+1 (odd) consumes buffer B
        if (t + 3 < 128) {
            wait_tile(t + 3);
            if (isX) load_vec(t + 3, qb); else load_hm(t + 3, hb);
        }
        barrier_nodrain();
        cur ^= 1;
    }

    float* finp = isX ? (hxfin + (long)wg * 16 * 256) : hmfin;
#pragma unroll
    for (int ct = 0; ct < 2; ct++) {
        const int ob = v * 32 + ct * 16 + l15;
#pragma unroll
        for (int r = 0; r < 4; r++)
            finp[(quad * 4 + r) * 256 + ob] = st[ct * 4 + r];
    }
}

// ---------------- K4: cosine gate at t=T-1 -> output ----------------
__global__ void finalize(const float* __restrict__ hxfin, const float* __restrict__ hmfin,
                         const float* __restrict__ W_sx, const float* __restrict__ b_sx,
                         const float* __restrict__ W_sm, const float* __restrict__ b_sm,
                         float* __restrict__ out)
{
    const int b = blockIdx.x;      // 256
    const int lane = threadIdx.x;  // 64
    float qx[4], qm[4];
#pragma unroll
    for (int s = 0; s < 4; s++) {
        float px = 0.f, pm = 0.f;
#pragma unroll
        for (int i = 0; i < 4; i++) {
            int h = i * 64 + lane;
            px += W_sx[s * 256 + h] * hxfin[b * 256 + h];
            pm += W_sm[s * 256 + h] * hmfin[h];
        }
        for (int off = 32; off; off >>= 1) { px += __shfl_xor(px, off); pm += __shfl_xor(pm, off); }
        qx[s] = px + b_sx[s];
        qm[s] = pm + b_sm[s];
    }
    float num = 0.f, nx = 0.f, nm = 0.f;
#pragma unroll
    for (int s = 0; s < 4; s++) { num += qx[s] * qm[s]; nx += qx[s] * qx[s]; nm += qm[s] * qm[s]; }
    const float den = fmaxf(sqrtf(nx), 1e-8f) * fmaxf(sqrtf(nm), 1e-8f);
    const float g = 1.0f / (1.0f + __expf(-num / den));
#pragma unroll
    for (int i = 0; i < 4; i++) {
        int h = i * 64 + lane;
        out[b * 256 + h] = g * hxfin[b * 256 + h] + (1.0f - g) * hmfin[h];
    }
}

extern "C" void kernel_launch(void* const* d_in, const int* in_sizes, int n_in,
                              void* d_out, int out_size, void* d_ws, size_t ws_size,
                              hipStream_t stream)
{
    (void)in_sizes; (void)n_in; (void)out_size; (void)ws_size;
    const float* x      = (const float*)d_in[0];
    const float* W_emb  = (const float*)d_in[1];
    const float* b_emb  = (const float*)d_in[2];
    const float* gamma  = (const float*)d_in[3];
    const float* beta   = (const float*)d_in[4];
    const float* memory = (const float*)d_in[5];
    const float* w_ih_x = (const float*)d_in[6];
    const float* w_hh_x = (const float*)d_in[7];
    const float* b_ih_x = (const float*)d_in[8];
    const float* b_hh_x = (const float*)d_in[9];
    const float* w_ih_m = (const float*)d_in[10];
    const float* w_hh_m = (const float*)d_in[11];
    const float* b_ih_m = (const float*)d_in[12];
    const float* b_hh_m = (const float*)d_in[13];
    const float* W_sx   = (const float*)d_in[14];
    const float* b_sx   = (const float*)d_in[15];
    const float* W_sm   = (const float*)d_in[16];
    const float* b_sm   = (const float*)d_in[17];
    float* out = (float*)d_out;
    char* ws = (char*)d_ws;

    __bf16* xb    = (__bf16*)(ws + OFF_XB);
    __bf16* wembb = (__bf16*)(ws + OFF_WEMB);
    __bf16* whxb  = (__bf16*)(ws + OFF_WHX);
    __bf16* whmb  = (__bf16*)(ws + OFF_WHM);
    float*  sums  = (float*)(ws + OFF_SUM);
    float*  ssqs  = (float*)(ws + OFF_SSQ);
    int*    flags = (int*)(ws + OFF_FLAGS);
    float*  biasx = (float*)(ws + OFF_BIASX);
    __bf16* gim   = (__bf16*)(ws + OFF_GIM);
    __bf16* eact  = (__bf16*)(ws + OFF_EACT);
    __bf16* gperm = (__bf16*)(ws + OFF_GI);
    float*  hxf   = (float*)(ws + OFF_HXF);
    float*  hmf   = (float*)(ws + OFF_HMF);
    __bf16* wpx   = (__bf16*)(ws + OFF_WPX);

    prep<<<18432, 256, 0, stream>>>(x, W_emb, w_hh_x, w_hh_m, xb, wembb, whxb, whmb, sums, flags);
    gemm_e<<<dim3(256, 8), 256, 0, stream>>>(xb, wembb, b_emb, eact, sums, ssqs, 128, 1024);
    build_misc<<<3840, 64, 0, stream>>>(w_ih_x, b_ih_x, b_hh_x, sums, ssqs, gamma, beta, wpx, biasx,
                                        memory, w_ih_m, b_ih_m, b_hh_m, gim);
    fused<<<17 + 512, 512, 0, stream>>>(eact, wpx, biasx, gperm, gim, whxb, whmb,
                                        b_hh_x, b_hh_m, hxf, hmf, flags);
    finalize<<<256, 64, 0, stream>>>(hxf, hmf, W_sx, b_sx, W_sm, b_sm, out);
}